// Round 1
// baseline (1029.005 us; speedup 1.0000x reference)
//
#include <hip/hip_runtime.h>

#define N_NODES 100000
#define N_EDGES 1600000
#define IN_C 64
#define HID_C 64
#define OUT_C 16

// ---------------------------------------------------------------------------
// Edge aggregation layer 1: msg[dst] += x[src]; deg[dst] += 1 (c==0 lane).
// One thread per (edge, channel). Consecutive threads = consecutive channels
// of one edge -> coalesced gather read and coalesced atomic target region.
// ---------------------------------------------------------------------------
__global__ __launch_bounds__(256) void k_agg1(
    const float* __restrict__ x, const int* __restrict__ src,
    const int* __restrict__ dst, float* __restrict__ msg,
    float* __restrict__ deg) {
  long long idx = (long long)blockIdx.x * blockDim.x + threadIdx.x;
  if (idx >= (long long)N_EDGES * IN_C) return;
  int e = (int)(idx >> 6);
  int c = (int)(idx & 63);
  int s = src[e];
  int d = dst[e];
  float v = x[(long long)s * IN_C + c];
  atomicAdd(&msg[(long long)d * IN_C + c], v);
  if (c == 0) atomicAdd(&deg[d], 1.0f);
}

// Edge aggregation layer 2: msg[dst] += h[src] (deg already known).
__global__ __launch_bounds__(256) void k_agg2(
    const float* __restrict__ h, const int* __restrict__ src,
    const int* __restrict__ dst, float* __restrict__ msg) {
  long long idx = (long long)blockIdx.x * blockDim.x + threadIdx.x;
  if (idx >= (long long)N_EDGES * HID_C) return;
  int e = (int)(idx >> 6);
  int c = (int)(idx & 63);
  int s = src[e];
  int d = dst[e];
  float v = h[(long long)s * HID_C + c];
  atomicAdd(&msg[(long long)d * HID_C + c], v);
}

// ---------------------------------------------------------------------------
// Layer 1 dense part: h = relu(mean @ W1_l + b1 + x @ W1_r)
// Block = 256 threads = 4 nodes x 64 out-channels. W1_l/W1_r staged in LDS
// (32 KiB). Each thread does a K=64 dot in fp32.
// ---------------------------------------------------------------------------
__global__ __launch_bounds__(256) void k_layer1(
    const float* __restrict__ x, const float* __restrict__ msg,
    const float* __restrict__ deg, const float* __restrict__ Wl,
    const float* __restrict__ b, const float* __restrict__ Wr,
    float* __restrict__ h) {
  __shared__ float sWl[IN_C * HID_C];
  __shared__ float sWr[IN_C * HID_C];
  for (int i = threadIdx.x; i < IN_C * HID_C; i += 256) {
    sWl[i] = Wl[i];
    sWr[i] = Wr[i];
  }
  __syncthreads();
  int ln = threadIdx.x >> 6;                 // 0..3
  int o = threadIdx.x & 63;                  // out channel
  long long n = (long long)blockIdx.x * 4 + ln;
  if (n >= N_NODES) return;
  float inv = 1.0f / fmaxf(deg[n], 1.0f);
  float acc = b[o];
  const float* __restrict__ xr = x + n * IN_C;
  const float* __restrict__ mr = msg + n * IN_C;
#pragma unroll
  for (int k = 0; k < IN_C; ++k) {
    acc += mr[k] * inv * sWl[k * HID_C + o] + xr[k] * sWr[k * HID_C + o];
  }
  h[n * HID_C + o] = fmaxf(acc, 0.0f);
}

// ---------------------------------------------------------------------------
// Layer 2 dense part: out = mean2 @ W2_l + b2 + h @ W2_r  (no relu)
// Block = 256 threads = 16 nodes x 16 out-channels. Weights in LDS (8 KiB).
// ---------------------------------------------------------------------------
__global__ __launch_bounds__(256) void k_layer2(
    const float* __restrict__ h, const float* __restrict__ msg,
    const float* __restrict__ deg, const float* __restrict__ Wl,
    const float* __restrict__ b, const float* __restrict__ Wr,
    float* __restrict__ out) {
  __shared__ float sWl[HID_C * OUT_C];
  __shared__ float sWr[HID_C * OUT_C];
  for (int i = threadIdx.x; i < HID_C * OUT_C; i += 256) {
    sWl[i] = Wl[i];
    sWr[i] = Wr[i];
  }
  __syncthreads();
  int ln = threadIdx.x >> 4;                 // 0..15
  int o = threadIdx.x & 15;                  // out channel
  long long n = (long long)blockIdx.x * 16 + ln;
  if (n >= N_NODES) return;
  float inv = 1.0f / fmaxf(deg[n], 1.0f);
  float acc = b[o];
  const float* __restrict__ hr = h + n * HID_C;
  const float* __restrict__ mr = msg + n * HID_C;
#pragma unroll
  for (int k = 0; k < HID_C; ++k) {
    acc += mr[k] * inv * sWl[k * OUT_C + o] + hr[k] * sWr[k * OUT_C + o];
  }
  out[n * OUT_C + o] = acc;
}

extern "C" void kernel_launch(void* const* d_in, const int* in_sizes, int n_in,
                              void* d_out, int out_size, void* d_ws, size_t ws_size,
                              hipStream_t stream) {
  const float* x   = (const float*)d_in[0];
  const int* edge  = (const int*)d_in[1];
  const int* src   = edge;             // edge_index[0]
  const int* dst   = edge + N_EDGES;   // edge_index[1]
  const float* W1l = (const float*)d_in[2];
  const float* b1  = (const float*)d_in[3];
  const float* W1r = (const float*)d_in[4];
  const float* W2l = (const float*)d_in[5];
  const float* b2  = (const float*)d_in[6];
  const float* W2r = (const float*)d_in[7];
  float* out = (float*)d_out;

  // workspace: msg (reused both layers) | h | deg
  float* msg = (float*)d_ws;
  float* h   = msg + (size_t)N_NODES * IN_C;
  float* deg = h + (size_t)N_NODES * HID_C;

  hipMemsetAsync(msg, 0, (size_t)N_NODES * IN_C * sizeof(float), stream);
  hipMemsetAsync(deg, 0, (size_t)N_NODES * sizeof(float), stream);

  {
    long long total = (long long)N_EDGES * IN_C;
    int blocks = (int)((total + 255) / 256);
    k_agg1<<<blocks, 256, 0, stream>>>(x, src, dst, msg, deg);
  }
  {
    int blocks = (N_NODES + 3) / 4;
    k_layer1<<<blocks, 256, 0, stream>>>(x, msg, deg, W1l, b1, W1r, h);
  }

  hipMemsetAsync(msg, 0, (size_t)N_NODES * HID_C * sizeof(float), stream);

  {
    long long total = (long long)N_EDGES * HID_C;
    int blocks = (int)((total + 255) / 256);
    k_agg2<<<blocks, 256, 0, stream>>>(h, src, dst, msg);
  }
  {
    int blocks = (N_NODES + 15) / 16;
    k_layer2<<<blocks, 256, 0, stream>>>(h, msg, deg, W2l, b2, W2r, out);
  }
}

// Round 2
// 445.741 us; speedup vs baseline: 2.3085x; 2.3085x over previous
//
#include <hip/hip_runtime.h>

#define N_NODES 100000
#define N_EDGES 1600000
#define IN_C 64
#define HID_C 64
#define OUT_C 16
#define NB_SCAN 391  // ceil(N_NODES/256)

// ---------------------------------------------------------------------------
// CSR build: histogram -> 3-kernel exclusive scan -> scatter
// ---------------------------------------------------------------------------
__global__ __launch_bounds__(256) void k_hist(const int* __restrict__ dst,
                                              int* __restrict__ cnt) {
  int e = blockIdx.x * 256 + threadIdx.x;
  if (e < N_EDGES) atomicAdd(&cnt[dst[e]], 1);
}

__global__ __launch_bounds__(256) void k_scan_a(const int* __restrict__ cnt,
                                                int* __restrict__ bsum) {
  __shared__ int s[256];
  int i = blockIdx.x * 256 + threadIdx.x;
  s[threadIdx.x] = (i < N_NODES) ? cnt[i] : 0;
  __syncthreads();
  for (int st = 128; st > 0; st >>= 1) {
    if (threadIdx.x < st) s[threadIdx.x] += s[threadIdx.x + st];
    __syncthreads();
  }
  if (threadIdx.x == 0) bsum[blockIdx.x] = s[0];
}

__global__ __launch_bounds__(512) void k_scan_b(const int* __restrict__ bsum,
                                                int* __restrict__ bscan) {
  __shared__ int s[512];
  int t = threadIdx.x;
  int v = (t < NB_SCAN) ? bsum[t] : 0;
  s[t] = v;
  __syncthreads();
  for (int st = 1; st < 512; st <<= 1) {
    int add = (t >= st) ? s[t - st] : 0;
    __syncthreads();
    s[t] += add;
    __syncthreads();
  }
  if (t < NB_SCAN) bscan[t] = s[t] - v;  // exclusive
}

__global__ __launch_bounds__(256) void k_scan_c(const int* __restrict__ cnt,
                                                const int* __restrict__ bscan,
                                                int* __restrict__ rowstart,
                                                int* __restrict__ cursor) {
  __shared__ int s[256];
  int t = threadIdx.x;
  int i = blockIdx.x * 256 + t;
  int v = (i < N_NODES) ? cnt[i] : 0;
  s[t] = v;
  __syncthreads();
  for (int st = 1; st < 256; st <<= 1) {
    int add = (t >= st) ? s[t - st] : 0;
    __syncthreads();
    s[t] += add;
    __syncthreads();
  }
  int ex = s[t] - v + bscan[blockIdx.x];
  if (i < N_NODES) {
    rowstart[i] = ex;
    cursor[i] = ex;
  }
}

__global__ __launch_bounds__(256) void k_scatter(const int* __restrict__ src,
                                                 const int* __restrict__ dst,
                                                 int* __restrict__ cursor,
                                                 int* __restrict__ csr) {
  int e = blockIdx.x * 256 + threadIdx.x;
  if (e < N_EDGES) {
    int pos = atomicAdd(&cursor[dst[e]], 1);
    csr[pos] = src[e];
  }
}

// ---------------------------------------------------------------------------
// GEMM 1: p = x @ Wl ; q = x @ Wr + b     (M=100k, K=64, N=64+64)
// Block: 64 nodes x 128 cols, 256 threads, each 4 nodes x 8 cols.
// ---------------------------------------------------------------------------
__global__ __launch_bounds__(256) void k_gemm1(
    const float* __restrict__ x, const float* __restrict__ Wl,
    const float* __restrict__ Wr, const float* __restrict__ b,
    float* __restrict__ p, float* __restrict__ q) {
  __shared__ float sA[64 * 66];   // padded: bank-conflict-free compute reads
  __shared__ float sW[64 * 128];  // [k][0..63]=Wl row k, [k][64..127]=Wr row k
  int t = threadIdx.x;
  int n0 = blockIdx.x * 64;

  for (int i = t; i < 64 * 64; i += 256) {
    int r = i >> 6, c = i & 63;
    int n = n0 + r;
    sA[r * 66 + c] = (n < N_NODES) ? x[n * 64 + c] : 0.0f;
  }
  for (int f = t; f < 2048; f += 256) {  // 2048 float4s
    int k = f >> 5, c4 = f & 31;
    float4 w = (c4 < 16) ? *(const float4*)&Wl[k * 64 + c4 * 4]
                         : *(const float4*)&Wr[k * 64 + (c4 - 16) * 4];
    *(float4*)&sW[k * 128 + c4 * 4] = w;
  }
  __syncthreads();

  int tx = t & 15;  // col group: cols tx*8 .. tx*8+7
  int ty = t >> 4;  // node group: nodes ty*4 .. ty*4+3
  float acc[4][8];
#pragma unroll
  for (int i = 0; i < 4; ++i)
#pragma unroll
    for (int j = 0; j < 8; ++j) acc[i][j] = 0.0f;

  for (int k = 0; k < 64; ++k) {
    float4 w0 = *(float4*)&sW[k * 128 + tx * 8];
    float4 w1 = *(float4*)&sW[k * 128 + tx * 8 + 4];
    float wv[8] = {w0.x, w0.y, w0.z, w0.w, w1.x, w1.y, w1.z, w1.w};
#pragma unroll
    for (int i = 0; i < 4; ++i) {
      float a = sA[(ty * 4 + i) * 66 + k];
#pragma unroll
      for (int j = 0; j < 8; ++j) acc[i][j] += a * wv[j];
    }
  }

#pragma unroll
  for (int i = 0; i < 4; ++i) {
    int n = n0 + ty * 4 + i;
    if (n >= N_NODES) break;
    if (tx < 8) {
      int c = tx * 8;
      float4 o0 = {acc[i][0], acc[i][1], acc[i][2], acc[i][3]};
      float4 o1 = {acc[i][4], acc[i][5], acc[i][6], acc[i][7]};
      *(float4*)&p[n * 64 + c] = o0;
      *(float4*)&p[n * 64 + c + 4] = o1;
    } else {
      int c = (tx - 8) * 8;
      float4 o0 = {acc[i][0] + b[c], acc[i][1] + b[c + 1], acc[i][2] + b[c + 2],
                   acc[i][3] + b[c + 3]};
      float4 o1 = {acc[i][4] + b[c + 4], acc[i][5] + b[c + 5],
                   acc[i][6] + b[c + 6], acc[i][7] + b[c + 7]};
      *(float4*)&q[n * 64 + c] = o0;
      *(float4*)&q[n * 64 + c + 4] = o1;
    }
  }
}

// ---------------------------------------------------------------------------
// Fuse 1: h[n] = relu(mean_j p1[csr_j] + q1[n])   (in place over q1)
// One wave per node; lane = channel.
// ---------------------------------------------------------------------------
__global__ __launch_bounds__(256) void k_fuse1(
    const float* __restrict__ p1, const int* __restrict__ rowstart,
    const int* __restrict__ cnt, const int* __restrict__ csr,
    float* __restrict__ q1h) {
  int t = threadIdx.x;
  int n = blockIdx.x * 4 + (t >> 6);
  int c = t & 63;
  int row = rowstart[n];
  int deg = cnt[n];
  float acc = 0.0f;
  int j = 0;
  for (; j + 4 <= deg; j += 4) {
    int s0 = csr[row + j];
    int s1 = csr[row + j + 1];
    int s2 = csr[row + j + 2];
    int s3 = csr[row + j + 3];
    float v0 = p1[s0 * 64 + c];
    float v1 = p1[s1 * 64 + c];
    float v2 = p1[s2 * 64 + c];
    float v3 = p1[s3 * 64 + c];
    acc += v0 + v1 + v2 + v3;
  }
  for (; j < deg; ++j) acc += p1[csr[row + j] * 64 + c];
  float inv = 1.0f / fmaxf((float)deg, 1.0f);
  int o = n * 64 + c;
  q1h[o] = fmaxf(acc * inv + q1h[o], 0.0f);
}

// ---------------------------------------------------------------------------
// GEMM 2: p2 = h @ W2l ; q2 = h @ W2r + b2   (M=100k, K=64, N=16+16)
// Block: 128 nodes x 32 cols, 256 threads, each 4 nodes x 4 cols.
// ---------------------------------------------------------------------------
__global__ __launch_bounds__(256) void k_gemm2(
    const float* __restrict__ h, const float* __restrict__ Wl,
    const float* __restrict__ Wr, const float* __restrict__ b,
    float* __restrict__ p, float* __restrict__ q) {
  __shared__ float sA[128 * 66];
  __shared__ float sW[64 * 32];  // [k][0..15]=W2l row k, [k][16..31]=W2r row k
  int t = threadIdx.x;
  int n0 = blockIdx.x * 128;

  for (int i = t; i < 128 * 64; i += 256) {
    int r = i >> 6, c = i & 63;
    int n = n0 + r;
    sA[r * 66 + c] = (n < N_NODES) ? h[n * 64 + c] : 0.0f;
  }
  for (int f = t; f < 512; f += 256) {  // 512 float4s
    int k = f >> 3, c4 = f & 7;
    float4 w = (c4 < 4) ? *(const float4*)&Wl[k * 16 + c4 * 4]
                        : *(const float4*)&Wr[k * 16 + (c4 - 4) * 4];
    *(float4*)&sW[k * 32 + c4 * 4] = w;
  }
  __syncthreads();

  int tx = t & 7;  // col group: cols tx*4 .. tx*4+3
  int ty = t >> 3; // node group: nodes ty*4 .. ty*4+3
  float acc[4][4];
#pragma unroll
  for (int i = 0; i < 4; ++i)
#pragma unroll
    for (int j = 0; j < 4; ++j) acc[i][j] = 0.0f;

  for (int k = 0; k < 64; ++k) {
    float4 w = *(float4*)&sW[k * 32 + tx * 4];
    float wv[4] = {w.x, w.y, w.z, w.w};
#pragma unroll
    for (int i = 0; i < 4; ++i) {
      float a = sA[(ty * 4 + i) * 66 + k];
#pragma unroll
      for (int j = 0; j < 4; ++j) acc[i][j] += a * wv[j];
    }
  }

#pragma unroll
  for (int i = 0; i < 4; ++i) {
    int n = n0 + ty * 4 + i;
    if (n >= N_NODES) break;
    if (tx < 4) {
      int c = tx * 4;
      float4 o = {acc[i][0], acc[i][1], acc[i][2], acc[i][3]};
      *(float4*)&p[n * 16 + c] = o;
    } else {
      int c = (tx - 4) * 4;
      float4 o = {acc[i][0] + b[c], acc[i][1] + b[c + 1], acc[i][2] + b[c + 2],
                  acc[i][3] + b[c + 3]};
      *(float4*)&q[n * 16 + c] = o;
    }
  }
}

// ---------------------------------------------------------------------------
// Fuse 2: out[n] = mean_j p2[csr_j] + q2[n]
// 16 lanes per node; wave handles 4 nodes.
// ---------------------------------------------------------------------------
__global__ __launch_bounds__(256) void k_fuse2(
    const float* __restrict__ p2, const float* __restrict__ q2,
    const int* __restrict__ rowstart, const int* __restrict__ cnt,
    const int* __restrict__ csr, float* __restrict__ out) {
  int t = threadIdx.x;
  int n = blockIdx.x * 16 + (t >> 4);
  int c = t & 15;
  int row = rowstart[n];
  int deg = cnt[n];
  float acc = 0.0f;
  int j = 0;
  for (; j + 4 <= deg; j += 4) {
    int s0 = csr[row + j];
    int s1 = csr[row + j + 1];
    int s2 = csr[row + j + 2];
    int s3 = csr[row + j + 3];
    float v0 = p2[s0 * 16 + c];
    float v1 = p2[s1 * 16 + c];
    float v2 = p2[s2 * 16 + c];
    float v3 = p2[s3 * 16 + c];
    acc += v0 + v1 + v2 + v3;
  }
  for (; j < deg; ++j) acc += p2[csr[row + j] * 16 + c];
  float inv = 1.0f / fmaxf((float)deg, 1.0f);
  out[n * 16 + c] = acc * inv + q2[n * 16 + c];
}

extern "C" void kernel_launch(void* const* d_in, const int* in_sizes, int n_in,
                              void* d_out, int out_size, void* d_ws, size_t ws_size,
                              hipStream_t stream) {
  const float* x   = (const float*)d_in[0];
  const int* edge  = (const int*)d_in[1];
  const int* src   = edge;            // edge_index[0]
  const int* dst   = edge + N_EDGES;  // edge_index[1]
  const float* W1l = (const float*)d_in[2];
  const float* b1  = (const float*)d_in[3];
  const float* W1r = (const float*)d_in[4];
  const float* W2l = (const float*)d_in[5];
  const float* b2  = (const float*)d_in[6];
  const float* W2r = (const float*)d_in[7];
  float* out = (float*)d_out;

  // workspace layout (all 4-byte elems; float4 bases stay 16B-aligned)
  int* cnt      = (int*)d_ws;          // 100000
  int* rowstart = cnt + N_NODES;       // 100000
  int* cursor   = rowstart + N_NODES;  // 100000
  int* bsum     = cursor + N_NODES;    // 512
  int* bscan    = bsum + 512;          // 512
  int* csr      = bscan + 512;         // 1600000
  float* p1     = (float*)(csr + N_EDGES);  // 6.4M floats
  float* q1h    = p1 + (size_t)N_NODES * HID_C;  // 6.4M floats (q1 -> h in place)
  float* p2     = p1;                  // layer-2 reuse (p1 dead after fuse1)
  float* q2     = p1 + (size_t)N_NODES * OUT_C;

  hipMemsetAsync(cnt, 0, N_NODES * sizeof(int), stream);

  int eb = (N_EDGES + 255) / 256;  // 6250
  k_hist<<<eb, 256, 0, stream>>>(dst, cnt);
  k_scan_a<<<NB_SCAN, 256, 0, stream>>>(cnt, bsum);
  k_scan_b<<<1, 512, 0, stream>>>(bsum, bscan);
  k_scan_c<<<NB_SCAN, 256, 0, stream>>>(cnt, bscan, rowstart, cursor);
  k_scatter<<<eb, 256, 0, stream>>>(src, dst, cursor, csr);

  k_gemm1<<<(N_NODES + 63) / 64, 256, 0, stream>>>(x, W1l, W1r, b1, p1, q1h);
  k_fuse1<<<(N_NODES + 3) / 4, 256, 0, stream>>>(p1, rowstart, cnt, csr, q1h);

  k_gemm2<<<(N_NODES + 127) / 128, 256, 0, stream>>>(q1h, W2l, W2r, b2, p2, q2);
  k_fuse2<<<(N_NODES + 15) / 16, 256, 0, stream>>>(p2, q2, rowstart, cnt, csr, out);
}

// Round 3
// 296.003 us; speedup vs baseline: 3.4763x; 1.5059x over previous
//
#include <hip/hip_runtime.h>
#include <hip/hip_fp16.h>

#define N_NODES 100000
#define N_EDGES 1600000
#define IN_C 64
#define HID_C 64
#define OUT_C 16

#define GB 256        // blocks in edge-binning passes (6250 edges each)
#define EPB 6250      // edges per block (256*6250 = 1.6M exactly)
#define BSH 8         // bucket shift: 256 nodes per bucket
#define NBKT 391      // ceil(100000/256)
#define LM (NBKT*GB)  // count-matrix length = 100096

// ---------------------------------------------------------------------------
// Pass A1: per-block bucket histogram -> M[bucket*GB + block]
// ---------------------------------------------------------------------------
__global__ __launch_bounds__(256) void k_count(const int* __restrict__ dst,
                                               int* __restrict__ M) {
  __shared__ int h[NBKT];
  for (int i = threadIdx.x; i < NBKT; i += 256) h[i] = 0;
  __syncthreads();
  int base = blockIdx.x * EPB;
  for (int e = base + threadIdx.x; e < base + EPB; e += 256)
    atomicAdd(&h[dst[e] >> BSH], 1);
  __syncthreads();
  for (int i = threadIdx.x; i < NBKT; i += 256) M[i * GB + blockIdx.x] = h[i];
}

// ---------------------------------------------------------------------------
// Generic 3-kernel exclusive scan (L arbitrary, nb = ceil(L/256) <= 512)
// ---------------------------------------------------------------------------
__global__ __launch_bounds__(256) void gscan_a(const int* __restrict__ in,
                                               int* __restrict__ bsum, int L) {
  __shared__ int s[256];
  int i = blockIdx.x * 256 + threadIdx.x;
  s[threadIdx.x] = (i < L) ? in[i] : 0;
  __syncthreads();
  for (int st = 128; st > 0; st >>= 1) {
    if (threadIdx.x < st) s[threadIdx.x] += s[threadIdx.x + st];
    __syncthreads();
  }
  if (threadIdx.x == 0) bsum[blockIdx.x] = s[0];
}

__global__ __launch_bounds__(512) void gscan_b(int* __restrict__ bsum, int nb) {
  __shared__ int s[512];
  int t = threadIdx.x;
  int v = (t < nb) ? bsum[t] : 0;
  s[t] = v;
  __syncthreads();
  for (int st = 1; st < 512; st <<= 1) {
    int a = (t >= st) ? s[t - st] : 0;
    __syncthreads();
    s[t] += a;
    __syncthreads();
  }
  if (t < nb) bsum[t] = s[t] - v;  // exclusive
}

__global__ __launch_bounds__(256) void gscan_c(const int* __restrict__ in,
                                               const int* __restrict__ bsum,
                                               int* __restrict__ outEx, int L) {
  __shared__ int s[256];
  int t = threadIdx.x;
  int i = blockIdx.x * 256 + t;
  int v = (i < L) ? in[i] : 0;
  s[t] = v;
  __syncthreads();
  for (int st = 1; st < 256; st <<= 1) {
    int a = (t >= st) ? s[t - st] : 0;
    __syncthreads();
    s[t] += a;
    __syncthreads();
  }
  if (i < L) outEx[i] = s[t] - v + bsum[blockIdx.x];
}

// ---------------------------------------------------------------------------
// Pass A2: scatter edges into bucket-binned array. Writes cluster on each
// bucket's frontier -> L2-absorbed. Entry packs (src<<8)|dst_local.
// ---------------------------------------------------------------------------
__global__ __launch_bounds__(256) void k_binscatter(
    const int* __restrict__ src, const int* __restrict__ dst,
    const int* __restrict__ Mex, int* __restrict__ binned) {
  __shared__ int cur[NBKT];
  for (int i = threadIdx.x; i < NBKT; i += 256)
    cur[i] = Mex[i * GB + blockIdx.x];
  __syncthreads();
  int base = blockIdx.x * EPB;
  for (int e = base + threadIdx.x; e < base + EPB; e += 256) {
    int d = dst[e];
    int pos = atomicAdd(&cur[d >> BSH], 1);
    binned[pos] = (src[e] << BSH) | (d & 255);
  }
}

// Pass B1: per-bucket node counts (exact, no global atomics).
__global__ __launch_bounds__(256) void k_nodecnt(const int* __restrict__ binned,
                                                 const int* __restrict__ Mex,
                                                 int* __restrict__ cnt) {
  int b = blockIdx.x;
  __shared__ int h[256];
  h[threadIdx.x] = 0;
  __syncthreads();
  int start = Mex[b * GB];
  int end = (b == NBKT - 1) ? N_EDGES : Mex[(b + 1) * GB];
  for (int i = start + threadIdx.x; i < end; i += 256)
    atomicAdd(&h[binned[i] & 255], 1);
  __syncthreads();
  int n = (b << BSH) + threadIdx.x;
  if (n < N_NODES) cnt[n] = h[threadIdx.x];
}

// Pass B2: final scatter. csr writes confined to this bucket's ~16KB span.
__global__ __launch_bounds__(256) void k_finalscatter(
    const int* __restrict__ binned, const int* __restrict__ Mex,
    const int* __restrict__ rowstart, int* __restrict__ csr) {
  int b = blockIdx.x;
  __shared__ int cur[256];
  int n = (b << BSH) + threadIdx.x;
  cur[threadIdx.x] = (n < N_NODES) ? rowstart[n] : 0;
  __syncthreads();
  int start = Mex[b * GB];
  int end = (b == NBKT - 1) ? N_EDGES : Mex[(b + 1) * GB];
  for (int i = start + threadIdx.x; i < end; i += 256) {
    int v = binned[i];
    int pos = atomicAdd(&cur[v & 255], 1);
    csr[pos] = v >> BSH;
  }
}

// ---------------------------------------------------------------------------
// GEMM 1: p(fp16) = x @ Wl ; q(fp32) = x @ Wr + b   (M=100k, K=64, N=64+64)
// ---------------------------------------------------------------------------
__global__ __launch_bounds__(256) void k_gemm1(
    const float* __restrict__ x, const float* __restrict__ Wl,
    const float* __restrict__ Wr, const float* __restrict__ b,
    __half* __restrict__ p, float* __restrict__ q) {
  __shared__ float sA[64 * 66];
  __shared__ float sW[64 * 128];
  int t = threadIdx.x;
  int n0 = blockIdx.x * 64;

  for (int i = t; i < 64 * 64; i += 256) {
    int r = i >> 6, c = i & 63;
    int n = n0 + r;
    sA[r * 66 + c] = (n < N_NODES) ? x[n * 64 + c] : 0.0f;
  }
  for (int f = t; f < 2048; f += 256) {
    int k = f >> 5, c4 = f & 31;
    float4 w = (c4 < 16) ? *(const float4*)&Wl[k * 64 + c4 * 4]
                         : *(const float4*)&Wr[k * 64 + (c4 - 16) * 4];
    *(float4*)&sW[k * 128 + c4 * 4] = w;
  }
  __syncthreads();

  int tx = t & 15;
  int ty = t >> 4;
  float acc[4][8];
#pragma unroll
  for (int i = 0; i < 4; ++i)
#pragma unroll
    for (int j = 0; j < 8; ++j) acc[i][j] = 0.0f;

  for (int k = 0; k < 64; ++k) {
    float4 w0 = *(float4*)&sW[k * 128 + tx * 8];
    float4 w1 = *(float4*)&sW[k * 128 + tx * 8 + 4];
    float wv[8] = {w0.x, w0.y, w0.z, w0.w, w1.x, w1.y, w1.z, w1.w};
#pragma unroll
    for (int i = 0; i < 4; ++i) {
      float a = sA[(ty * 4 + i) * 66 + k];
#pragma unroll
      for (int j = 0; j < 8; ++j) acc[i][j] += a * wv[j];
    }
  }

#pragma unroll
  for (int i = 0; i < 4; ++i) {
    int n = n0 + ty * 4 + i;
    if (n >= N_NODES) break;
    if (tx < 8) {
      int c = tx * 8;
      union { __half h[8]; float4 f; } u;
#pragma unroll
      for (int j = 0; j < 8; ++j) u.h[j] = __float2half(acc[i][j]);
      *(float4*)&p[(size_t)n * 64 + c] = u.f;
    } else {
      int c = (tx - 8) * 8;
      float4 o0 = {acc[i][0] + b[c], acc[i][1] + b[c + 1], acc[i][2] + b[c + 2],
                   acc[i][3] + b[c + 3]};
      float4 o1 = {acc[i][4] + b[c + 4], acc[i][5] + b[c + 5],
                   acc[i][6] + b[c + 6], acc[i][7] + b[c + 7]};
      *(float4*)&q[(size_t)n * 64 + c] = o0;
      *(float4*)&q[(size_t)n * 64 + c + 4] = o1;
    }
  }
}

// Fuse 1: h[n] = relu(mean_j p1[csr_j] + q1[n])  (in place over q1)
__global__ __launch_bounds__(256) void k_fuse1(
    const __half* __restrict__ p1, const int* __restrict__ rowstart,
    const int* __restrict__ cnt, const int* __restrict__ csr,
    float* __restrict__ q1h) {
  int t = threadIdx.x;
  int n = blockIdx.x * 4 + (t >> 6);
  int c = t & 63;
  int row = rowstart[n];
  int deg = cnt[n];
  float acc = 0.0f;
  int j = 0;
  for (; j + 4 <= deg; j += 4) {
    int s0 = csr[row + j];
    int s1 = csr[row + j + 1];
    int s2 = csr[row + j + 2];
    int s3 = csr[row + j + 3];
    float v0 = __half2float(p1[(size_t)s0 * 64 + c]);
    float v1 = __half2float(p1[(size_t)s1 * 64 + c]);
    float v2 = __half2float(p1[(size_t)s2 * 64 + c]);
    float v3 = __half2float(p1[(size_t)s3 * 64 + c]);
    acc += v0 + v1 + v2 + v3;
  }
  for (; j < deg; ++j) acc += __half2float(p1[(size_t)csr[row + j] * 64 + c]);
  float inv = 1.0f / fmaxf((float)deg, 1.0f);
  int o = n * 64 + c;
  q1h[o] = fmaxf(acc * inv + q1h[o], 0.0f);
}

// ---------------------------------------------------------------------------
// GEMM 2: p2(fp16) = h @ W2l ; q2(fp32) = h @ W2r + b2  (M=100k, K=64, N=16+16)
// ---------------------------------------------------------------------------
__global__ __launch_bounds__(256) void k_gemm2(
    const float* __restrict__ h, const float* __restrict__ Wl,
    const float* __restrict__ Wr, const float* __restrict__ b,
    __half* __restrict__ p, float* __restrict__ q) {
  __shared__ float sA[128 * 66];
  __shared__ float sW[64 * 32];
  int t = threadIdx.x;
  int n0 = blockIdx.x * 128;

  for (int i = t; i < 128 * 64; i += 256) {
    int r = i >> 6, c = i & 63;
    int n = n0 + r;
    sA[r * 66 + c] = (n < N_NODES) ? h[n * 64 + c] : 0.0f;
  }
  for (int f = t; f < 512; f += 256) {
    int k = f >> 3, c4 = f & 7;
    float4 w = (c4 < 4) ? *(const float4*)&Wl[k * 16 + c4 * 4]
                        : *(const float4*)&Wr[k * 16 + (c4 - 4) * 4];
    *(float4*)&sW[k * 32 + c4 * 4] = w;
  }
  __syncthreads();

  int tx = t & 7;
  int ty = t >> 3;
  float acc[4][4];
#pragma unroll
  for (int i = 0; i < 4; ++i)
#pragma unroll
    for (int j = 0; j < 4; ++j) acc[i][j] = 0.0f;

  for (int k = 0; k < 64; ++k) {
    float4 w = *(float4*)&sW[k * 32 + tx * 4];
    float wv[4] = {w.x, w.y, w.z, w.w};
#pragma unroll
    for (int i = 0; i < 4; ++i) {
      float a = sA[(ty * 4 + i) * 66 + k];
#pragma unroll
      for (int j = 0; j < 4; ++j) acc[i][j] += a * wv[j];
    }
  }

#pragma unroll
  for (int i = 0; i < 4; ++i) {
    int n = n0 + ty * 4 + i;
    if (n >= N_NODES) break;
    if (tx < 4) {
      int c = tx * 4;
      union { __half h[4]; float2 f; } u;
#pragma unroll
      for (int j = 0; j < 4; ++j) u.h[j] = __float2half(acc[i][j]);
      *(float2*)&p[(size_t)n * 16 + c] = u.f;
    } else {
      int c = (tx - 4) * 4;
      float4 o = {acc[i][0] + b[c], acc[i][1] + b[c + 1], acc[i][2] + b[c + 2],
                  acc[i][3] + b[c + 3]};
      *(float4*)&q[(size_t)n * 16 + c] = o;
    }
  }
}

// Fuse 2: out[n] = mean_j p2[csr_j] + q2[n]
__global__ __launch_bounds__(256) void k_fuse2(
    const __half* __restrict__ p2, const float* __restrict__ q2,
    const int* __restrict__ rowstart, const int* __restrict__ cnt,
    const int* __restrict__ csr, float* __restrict__ out) {
  int t = threadIdx.x;
  int n = blockIdx.x * 16 + (t >> 4);
  int c = t & 15;
  int row = rowstart[n];
  int deg = cnt[n];
  float acc = 0.0f;
  int j = 0;
  for (; j + 4 <= deg; j += 4) {
    int s0 = csr[row + j];
    int s1 = csr[row + j + 1];
    int s2 = csr[row + j + 2];
    int s3 = csr[row + j + 3];
    float v0 = __half2float(p2[(size_t)s0 * 16 + c]);
    float v1 = __half2float(p2[(size_t)s1 * 16 + c]);
    float v2 = __half2float(p2[(size_t)s2 * 16 + c]);
    float v3 = __half2float(p2[(size_t)s3 * 16 + c]);
    acc += v0 + v1 + v2 + v3;
  }
  for (; j < deg; ++j) acc += __half2float(p2[(size_t)csr[row + j] * 16 + c]);
  float inv = 1.0f / fmaxf((float)deg, 1.0f);
  out[n * 16 + c] = acc * inv + q2[n * 16 + c];
}

extern "C" void kernel_launch(void* const* d_in, const int* in_sizes, int n_in,
                              void* d_out, int out_size, void* d_ws, size_t ws_size,
                              hipStream_t stream) {
  const float* x   = (const float*)d_in[0];
  const int* edge  = (const int*)d_in[1];
  const int* src   = edge;            // edge_index[0]
  const int* dst   = edge + N_EDGES;  // edge_index[1]
  const float* W1l = (const float*)d_in[2];
  const float* b1  = (const float*)d_in[3];
  const float* W1r = (const float*)d_in[4];
  const float* W2l = (const float*)d_in[5];
  const float* b2  = (const float*)d_in[6];
  const float* W2r = (const float*)d_in[7];
  float* out = (float*)d_out;

  // workspace layout (4-byte units)
  int* cnt      = (int*)d_ws;          // 100000
  int* rowstart = cnt + N_NODES;       // 100000
  int* M        = rowstart + N_NODES;  // 100096 (count matrix, scanned in place)
  int* bsum     = M + LM;              // 512
  int* csr      = bsum + 512;          // 1600000
  float* regA   = (float*)(csr + N_EDGES);       // 6.4M floats (16B aligned)
  float* q1h    = regA + (size_t)N_NODES * 64;   // 6.4M floats
  __half* p1h   = (__half*)regA;       // 12.8 MB (fp16)
  int* binned   = (int*)regA;          // 6.4 MB  (dead before gemm1 writes p1h)
  __half* p2h   = (__half*)regA;       // 3.2 MB  (layer-2 reuse)
  float* q2     = regA + (size_t)N_NODES * 16;   // after p2h (6.4MB > 3.2MB)

  int nbM = (LM + 255) / 256;          // 391
  int nbN = (N_NODES + 255) / 256;     // 391

  // --- CSR build: binned two-pass scatter, no global fp/int contention ---
  k_count<<<GB, 256, 0, stream>>>(dst, M);
  gscan_a<<<nbM, 256, 0, stream>>>(M, bsum, LM);
  gscan_b<<<1, 512, 0, stream>>>(bsum, nbM);
  gscan_c<<<nbM, 256, 0, stream>>>(M, bsum, M, LM);  // in-place exclusive scan
  k_binscatter<<<GB, 256, 0, stream>>>(src, dst, M, binned);
  k_nodecnt<<<NBKT, 256, 0, stream>>>(binned, M, cnt);
  gscan_a<<<nbN, 256, 0, stream>>>(cnt, bsum, N_NODES);
  gscan_b<<<1, 512, 0, stream>>>(bsum, nbN);
  gscan_c<<<nbN, 256, 0, stream>>>(cnt, bsum, rowstart, N_NODES);
  k_finalscatter<<<NBKT, 256, 0, stream>>>(binned, M, rowstart, csr);

  // --- layer 1 ---
  k_gemm1<<<(N_NODES + 63) / 64, 256, 0, stream>>>(x, W1l, W1r, b1, p1h, q1h);
  k_fuse1<<<(N_NODES + 3) / 4, 256, 0, stream>>>(p1h, rowstart, cnt, csr, q1h);

  // --- layer 2 ---
  k_gemm2<<<(N_NODES + 127) / 128, 256, 0, stream>>>(q1h, W2l, W2r, b2, p2h, q2);
  k_fuse2<<<(N_NODES + 15) / 16, 256, 0, stream>>>(p2h, q2, rowstart, cnt, csr, out);
}